// Round 1
// baseline (573.067 us; speedup 1.0000x reference)
//
#include <hip/hip_runtime.h>
#include <hip/hip_bf16.h>
#include <stdint.h>

#define KDIM 1024
#define NPAD 512
#define NCOLS 405
#define SCORE_COLS 81
#define BBOX_COLS 324
#define NROWS 65536
#define FDIM 300

typedef short v8s __attribute__((ext_vector_type(8)));
typedef float v4f __attribute__((ext_vector_type(4)));

typedef __attribute__((address_space(3))) uint32_t lds_u32_t;
typedef __attribute__((address_space(1))) uint32_t glb_u32_t;

__device__ __forceinline__ void async16(void* lds, const void* g) {
    __builtin_amdgcn_global_load_lds((const glb_u32_t*)g, (lds_u32_t*)lds, 16, 0, 0);
}

__device__ __forceinline__ uint16_t f2bf(float f) {
    union { float f; uint32_t u; } c; c.f = f;
    uint32_t r = c.u + 0x7FFFu + ((c.u >> 16) & 1u);
    return (uint16_t)(r >> 16);
}

// ---- prep: W_total rows 0 (cls), 81..404 (bbox), 405..511 (zero pad) + biases
__global__ void fill_w(const float* __restrict__ Wcls, const float* __restrict__ bcls,
                       const float* __restrict__ Wbbox, const float* __restrict__ bbbox,
                       uint16_t* __restrict__ Wt, float* __restrict__ bt) {
    int idx = blockIdx.x * 256 + threadIdx.x;        // 512*1024 total
    int row = idx >> 10, k = idx & 1023;
    if (!(row >= 1 && row < 1 + 80)) {               // rows 1..80 done by fill_w_sem
        float v;
        if (row == 0) v = Wcls[k];
        else if (row < 81 + BBOX_COLS) v = Wbbox[(size_t)(row - 81) * KDIM + k];
        else v = 0.f;
        Wt[idx] = f2bf(v);
    }
    if (k == 0 && !(row >= 1 && row < 81)) {
        float b;
        if (row == 0) b = bcls[0];
        else if (row < 81 + BBOX_COLS) b = bbbox[row - 81];
        else b = 0.f;
        bt[row] = b;
    }
}

// ---- prep: W_total rows 1..80 = (8/||sem_row||) * (sem_row @ W_sem)
__global__ void fill_w_sem(const float* __restrict__ Wsem, const float* __restrict__ bsem,
                           const float* __restrict__ semm,
                           uint16_t* __restrict__ Wt, float* __restrict__ bt) {
    const int n = blockIdx.x;          // 0..79
    const int kq = blockIdx.y;         // 0..3
    const int tid = threadIdx.x;       // 256
    __shared__ float s_row[FDIM];
    __shared__ float red[256];
    __shared__ float s_scale, s_bdot;

    const float* sr = semm + (size_t)n * FDIM;
    float p = 0.f, pb = 0.f;
    for (int f = tid; f < FDIM; f += 256) {
        float v = sr[f];
        s_row[f] = v;
        p += v * v;
        pb += v * bsem[f];
    }
    red[tid] = p; __syncthreads();
    for (int s = 128; s > 0; s >>= 1) { if (tid < s) red[tid] += red[tid + s]; __syncthreads(); }
    float norm2 = red[0]; __syncthreads();
    red[tid] = pb; __syncthreads();
    for (int s = 128; s > 0; s >>= 1) { if (tid < s) red[tid] += red[tid + s]; __syncthreads(); }
    if (tid == 0) { s_scale = 8.0f / sqrtf(norm2); s_bdot = red[0]; }
    __syncthreads();
    const float scale = s_scale;
    if (kq == 0 && tid == 0) bt[1 + n] = scale * s_bdot;

    const int k = kq * 256 + tid;      // exactly one k per thread
    float acc = 0.f;
    #pragma unroll 8
    for (int f = 0; f < FDIM; ++f) acc += s_row[f] * Wsem[(size_t)f * KDIM + k];
    Wt[(size_t)(1 + n) * KDIM + k] = f2bf(scale * acc);
}

// ---- fused GEMM: out = x @ W_total^T + b_total, column-routed epilogue
__device__ __forceinline__ void compute_tile(const uint16_t* As, const uint16_t* Bs,
                                             int wr, int wc, int l16, int quad,
                                             v4f acc[4][4]) {
    v8s a[4], b[4];
    #pragma unroll
    for (int mi = 0; mi < 4; ++mi)
        a[mi] = *(const v8s*)&As[(wr * 64 + mi * 16 + l16) * 32 + quad * 8];
    #pragma unroll
    for (int ni = 0; ni < 4; ++ni)
        b[ni] = *(const v8s*)&Bs[(wc * 64 + ni * 16 + l16) * 32 + quad * 8];
    #pragma unroll
    for (int mi = 0; mi < 4; ++mi)
        #pragma unroll
        for (int ni = 0; ni < 4; ++ni)
            acc[mi][ni] = __builtin_amdgcn_mfma_f32_16x16x32_bf16(a[mi], b[ni], acc[mi][ni], 0, 0, 0);
}

__global__ __launch_bounds__(256, 2) void gemm_fused(
        const float* __restrict__ x, const uint16_t* __restrict__ Wt,
        const float* __restrict__ bt, float* __restrict__ out) {
    const int tid = threadIdx.x;
    const int wave = tid >> 6, lane = tid & 63;
    const int wr = wave & 1, wc = wave >> 1;
    const int quad = lane >> 4, l16 = lane & 15;
    const int ntile = blockIdx.x, mtile = blockIdx.y;

    __shared__ __align__(16) uint16_t As[2][128 * 32];
    __shared__ __align__(16) uint16_t Bs[2][128 * 32];

    const float*    xb = x  + (size_t)mtile * 128 * KDIM;
    const uint16_t* wb = Wt + (size_t)ntile * 128 * KDIM;

    const int colbase = ntile * 128 + wc * 64;
    float bias[4];
    #pragma unroll
    for (int ni = 0; ni < 4; ++ni) bias[ni] = bt[colbase + ni * 16 + l16];

    v4f acc[4][4];
    #pragma unroll
    for (int mi = 0; mi < 4; ++mi)
        #pragma unroll
        for (int ni = 0; ni < 4; ++ni)
            acc[mi][ni] = v4f{0.f, 0.f, 0.f, 0.f};

    float4 av[4];
    // ---- prologue: stage kt=0 into buffer 0
    #pragma unroll
    for (int i = 0; i < 2; ++i) {
        int c = i * 256 + tid, nr = c >> 2, kc = c & 3;
        async16(&Bs[0][c * 8], wb + (size_t)nr * KDIM + kc * 8);
    }
    #pragma unroll
    for (int i = 0; i < 4; ++i) {
        int c = i * 256 + tid, m = c >> 3, kc = c & 7;
        av[i] = *(const float4*)(xb + (size_t)m * KDIM + kc * 4);
    }
    #pragma unroll
    for (int i = 0; i < 4; ++i) {
        int c = i * 256 + tid, m = c >> 3, kc = c & 7;
        __hip_bfloat162 lo = __float22bfloat162_rn(make_float2(av[i].x, av[i].y));
        __hip_bfloat162 hi = __float22bfloat162_rn(make_float2(av[i].z, av[i].w));
        uint2 p; p.x = *(uint32_t*)&lo; p.y = *(uint32_t*)&hi;
        *(uint2*)&As[0][m * 32 + kc * 4] = p;
    }

    // ---- main loop: 1 barrier/iter, double-buffered LDS
    #pragma unroll 2
    for (int kt = 0; kt < 31; ++kt) {
        const int buf = kt & 1;
        __syncthreads();                       // staging(kt) visible; compute(kt-1) done
        // B(kt+1): async global->LDS, overlaps full compute phase
        #pragma unroll
        for (int i = 0; i < 2; ++i) {
            int c = i * 256 + tid, nr = c >> 2, kc = c & 3;
            async16(&Bs[buf ^ 1][c * 8], wb + (size_t)nr * KDIM + (kt + 1) * 32 + kc * 8);
        }
        // A(kt+1): issue fp32 loads now, consume after MFMAs
        #pragma unroll
        for (int i = 0; i < 4; ++i) {
            int c = i * 256 + tid, m = c >> 3, kc = c & 7;
            av[i] = *(const float4*)(xb + (size_t)m * KDIM + (kt + 1) * 32 + kc * 4);
        }
        compute_tile(As[buf], Bs[buf], wr, wc, l16, quad, acc);
        // convert + write A(kt+1) into the other buffer
        #pragma unroll
        for (int i = 0; i < 4; ++i) {
            int c = i * 256 + tid, m = c >> 3, kc = c & 7;
            __hip_bfloat162 lo = __float22bfloat162_rn(make_float2(av[i].x, av[i].y));
            __hip_bfloat162 hi = __float22bfloat162_rn(make_float2(av[i].z, av[i].w));
            uint2 p; p.x = *(uint32_t*)&lo; p.y = *(uint32_t*)&hi;
            *(uint2*)&As[buf ^ 1][m * 32 + kc * 4] = p;
        }
    }
    __syncthreads();
    compute_tile(As[1], Bs[1], wr, wc, l16, quad, acc);   // kt=31, buf=1

    // ---- epilogue: bias + column routing (scores cols 0..80, bbox 81..404)
    const int rowbase = mtile * 128 + wr * 64;
    #pragma unroll
    for (int ni = 0; ni < 4; ++ni) {
        const int c = colbase + ni * 16 + l16;
        if (c < NCOLS) {
            #pragma unroll
            for (int mi = 0; mi < 4; ++mi)
                #pragma unroll
                for (int r = 0; r < 4; ++r) {
                    int row = rowbase + mi * 16 + quad * 4 + r;
                    float v = acc[mi][ni][r] + bias[ni];
                    if (c < SCORE_COLS)
                        out[(size_t)row * SCORE_COLS + c] = v;
                    else
                        out[(size_t)NROWS * SCORE_COLS + (size_t)row * BBOX_COLS + (c - SCORE_COLS)] = v;
                }
        }
    }
}

extern "C" void kernel_launch(void* const* d_in, const int* in_sizes, int n_in,
                              void* d_out, int out_size, void* d_ws, size_t ws_size,
                              hipStream_t stream) {
    const float* x     = (const float*)d_in[0];
    const float* Wcls  = (const float*)d_in[1];
    const float* bcls  = (const float*)d_in[2];
    const float* Wsem  = (const float*)d_in[3];
    const float* bsem  = (const float*)d_in[4];
    const float* Wbbox = (const float*)d_in[5];
    const float* bbbox = (const float*)d_in[6];
    const float* semm  = (const float*)d_in[7];
    float* out = (float*)d_out;

    uint16_t* Wt = (uint16_t*)d_ws;                                  // 512*1024*2 = 1 MB
    float*    bt = (float*)((char*)d_ws + (size_t)NPAD * KDIM * 2);  // 2 KB

    fill_w<<<dim3(2048), dim3(256), 0, stream>>>(Wcls, bcls, Wbbox, bbbox, Wt, bt);
    fill_w_sem<<<dim3(80, 4), dim3(256), 0, stream>>>(Wsem, bsem, semm, Wt, bt);
    gemm_fused<<<dim3(4, 512), dim3(256), 0, stream>>>(x, Wt, bt, out);
}

// Round 2
// 524.925 us; speedup vs baseline: 1.0917x; 1.0917x over previous
//
#include <hip/hip_runtime.h>
#include <hip/hip_bf16.h>
#include <stdint.h>

#define KDIM 1024
#define NPAD 512
#define NCOLS 405
#define SCORE_COLS 81
#define BBOX_COLS 324
#define NROWS 65536
#define FDIM 300

// Blocked Wt layout: element (row, k) -> (k>>5)*16384 + row*32 + (k&31)
// i.e. [kt][512 cols][32 k] so B staging per K-iter is one dense 32 KB slab.

typedef short v8s __attribute__((ext_vector_type(8)));
typedef float v4f __attribute__((ext_vector_type(4)));

typedef __attribute__((address_space(3))) uint32_t lds_u32_t;
typedef __attribute__((address_space(1))) uint32_t glb_u32_t;

__device__ __forceinline__ void async16(void* lds, const void* g) {
    __builtin_amdgcn_global_load_lds((const glb_u32_t*)g, (lds_u32_t*)lds, 16, 0, 0);
}

__device__ __forceinline__ uint16_t f2bf(float f) {
    union { float f; uint32_t u; } c; c.f = f;
    uint32_t r = c.u + 0x7FFFu + ((c.u >> 16) & 1u);
    return (uint16_t)(r >> 16);
}

__device__ __forceinline__ size_t wt_off(int row, int k) {
    return (size_t)(k >> 5) * (NPAD * 32) + (size_t)row * 32 + (k & 31);
}

// ---- prep: W_total rows 0 (cls), 81..404 (bbox), 405..511 (zero pad) + biases
__global__ void fill_w(const float* __restrict__ Wcls, const float* __restrict__ bcls,
                       const float* __restrict__ Wbbox, const float* __restrict__ bbbox,
                       uint16_t* __restrict__ Wt, float* __restrict__ bt) {
    int idx = blockIdx.x * 256 + threadIdx.x;        // 512*1024 total
    int row = idx >> 10, k = idx & 1023;
    if (!(row >= 1 && row < 81)) {                   // rows 1..80 done by fill_w_sem
        float v;
        if (row == 0) v = Wcls[k];
        else if (row < 81 + BBOX_COLS) v = Wbbox[(size_t)(row - 81) * KDIM + k];
        else v = 0.f;
        Wt[wt_off(row, k)] = f2bf(v);
    }
    if (k == 0 && !(row >= 1 && row < 81)) {
        float b;
        if (row == 0) b = bcls[0];
        else if (row < 81 + BBOX_COLS) b = bbbox[row - 81];
        else b = 0.f;
        bt[row] = b;
    }
}

// ---- prep: W_total rows 1..80 = (8/||sem_row||) * (sem_row @ W_sem)
__global__ void fill_w_sem(const float* __restrict__ Wsem, const float* __restrict__ bsem,
                           const float* __restrict__ semm,
                           uint16_t* __restrict__ Wt, float* __restrict__ bt) {
    const int n = blockIdx.x;          // 0..79
    const int kq = blockIdx.y;         // 0..3
    const int tid = threadIdx.x;       // 256
    __shared__ float s_row[FDIM];
    __shared__ float red[256];
    __shared__ float s_scale, s_bdot;

    const float* sr = semm + (size_t)n * FDIM;
    float p = 0.f, pb = 0.f;
    for (int f = tid; f < FDIM; f += 256) {
        float v = sr[f];
        s_row[f] = v;
        p += v * v;
        pb += v * bsem[f];
    }
    red[tid] = p; __syncthreads();
    for (int s = 128; s > 0; s >>= 1) { if (tid < s) red[tid] += red[tid + s]; __syncthreads(); }
    float norm2 = red[0]; __syncthreads();
    red[tid] = pb; __syncthreads();
    for (int s = 128; s > 0; s >>= 1) { if (tid < s) red[tid] += red[tid + s]; __syncthreads(); }
    if (tid == 0) { s_scale = 8.0f / sqrtf(norm2); s_bdot = red[0]; }
    __syncthreads();
    const float scale = s_scale;
    if (kq == 0 && tid == 0) bt[1 + n] = scale * s_bdot;

    const int k = kq * 256 + tid;      // exactly one k per thread
    float acc = 0.f;
    #pragma unroll 8
    for (int f = 0; f < FDIM; ++f) acc += s_row[f] * Wsem[(size_t)f * KDIM + k];
    Wt[wt_off(1 + n, k)] = f2bf(scale * acc);
}

// ---- fused GEMM: one block = 64 rows x ALL 512 cols (x read exactly once)
#define A_STRIDE 36                     // bf16 elems per A row in LDS (pad for banks)
#define A_BUF_ELEMS (64 * A_STRIDE)     // 2304
#define B_BUF_ELEMS (NPAD * 32)         // 16384
#define SMEM_BYTES (2 * A_BUF_ELEMS * 2 + 2 * B_BUF_ELEMS * 2)  // 74752

__device__ __forceinline__ void compute_tile(const uint16_t* As, const uint16_t* Bs,
                                             int wc, int l16, int quad,
                                             v4f acc[4][4]) {
    v8s a[4], b[4];
    #pragma unroll
    for (int mi = 0; mi < 4; ++mi)
        a[mi] = *(const v8s*)&As[(mi * 16 + l16) * A_STRIDE + quad * 8];
    #pragma unroll
    for (int ni = 0; ni < 4; ++ni)
        b[ni] = *(const v8s*)&Bs[(wc * 64 + ni * 16 + l16) * 32 + quad * 8];
    #pragma unroll
    for (int mi = 0; mi < 4; ++mi)
        #pragma unroll
        for (int ni = 0; ni < 4; ++ni)
            acc[mi][ni] = __builtin_amdgcn_mfma_f32_16x16x32_bf16(a[mi], b[ni], acc[mi][ni], 0, 0, 0);
}

__global__ __launch_bounds__(512, 4) void gemm_fused(
        const float* __restrict__ x, const uint16_t* __restrict__ Wt,
        const float* __restrict__ bt, float* __restrict__ out) {
    const int tid = threadIdx.x;
    const int wave = tid >> 6, lane = tid & 63;
    const int wc = wave;                 // 8 waves: each 64 rows x 64 cols
    const int quad = lane >> 4, l16 = lane & 15;
    const int mtile = blockIdx.x;

    __shared__ __align__(16) char smem[SMEM_BYTES];
    uint16_t* As = (uint16_t*)smem;                        // [2][A_BUF_ELEMS]
    uint16_t* Bs = (uint16_t*)(smem + 2 * A_BUF_ELEMS * 2); // [2][B_BUF_ELEMS]

    const float* xb = x + (size_t)mtile * 64 * KDIM;

    const int colbase = wc * 64;
    float bias[4];
    #pragma unroll
    for (int ni = 0; ni < 4; ++ni) bias[ni] = bt[colbase + ni * 16 + l16];

    v4f acc[4][4];
    #pragma unroll
    for (int mi = 0; mi < 4; ++mi)
        #pragma unroll
        for (int ni = 0; ni < 4; ++ni)
            acc[mi][ni] = v4f{0.f, 0.f, 0.f, 0.f};

    const int am = tid >> 3, akc = tid & 7;       // A: row, float4-chunk
    float4 av;

    // ---- prologue: stage kt=0 into buffer 0
    #pragma unroll
    for (int i = 0; i < 4; ++i) {
        int c = i * 512 + tid;
        async16(&Bs[0 * B_BUF_ELEMS + c * 8], Wt + (size_t)c * 8);
    }
    av = *(const float4*)(xb + (size_t)am * KDIM + akc * 4);
    {
        __hip_bfloat162 lo = __float22bfloat162_rn(make_float2(av.x, av.y));
        __hip_bfloat162 hi = __float22bfloat162_rn(make_float2(av.z, av.w));
        uint2 p; p.x = *(uint32_t*)&lo; p.y = *(uint32_t*)&hi;
        *(uint2*)&As[0 * A_BUF_ELEMS + am * A_STRIDE + akc * 4] = p;
    }

    // ---- main loop: 1 barrier/iter, double-buffered LDS
    for (int kt = 0; kt < 31; ++kt) {
        const int buf = kt & 1;
        __syncthreads();                       // staging(kt) visible; compute(kt-1) done
        // B(kt+1): async global->LDS (dense 32 KB slab), overlaps compute
        #pragma unroll
        for (int i = 0; i < 4; ++i) {
            int c = i * 512 + tid;
            async16(&Bs[(buf ^ 1) * B_BUF_ELEMS + c * 8],
                    Wt + (size_t)(kt + 1) * B_BUF_ELEMS + (size_t)c * 8);
        }
        // A(kt+1): issue fp32 loads now, consume after MFMAs
        av = *(const float4*)(xb + (size_t)am * KDIM + (kt + 1) * 32 + akc * 4);
        compute_tile(&As[buf * A_BUF_ELEMS], &Bs[buf * B_BUF_ELEMS], wc, l16, quad, acc);
        // convert + write A(kt+1) into the other buffer
        {
            __hip_bfloat162 lo = __float22bfloat162_rn(make_float2(av.x, av.y));
            __hip_bfloat162 hi = __float22bfloat162_rn(make_float2(av.z, av.w));
            uint2 p; p.x = *(uint32_t*)&lo; p.y = *(uint32_t*)&hi;
            *(uint2*)&As[(buf ^ 1) * A_BUF_ELEMS + am * A_STRIDE + akc * 4] = p;
        }
    }
    __syncthreads();
    compute_tile(&As[1 * A_BUF_ELEMS], &Bs[1 * B_BUF_ELEMS], wc, l16, quad, acc);  // kt=31

    // ---- epilogue: stage through LDS (full-line coalesced writes)
    const int rowbase = mtile * 64;
    float* eps = (float*)smem;                 // [32][409]
    float* outb = out + (size_t)NROWS * SCORE_COLS;
    #pragma unroll
    for (int h = 0; h < 2; ++h) {
        __syncthreads();                       // LDS free for reuse / prev half done
        #pragma unroll
        for (int mi2 = 0; mi2 < 2; ++mi2) {
            const int mi = h * 2 + mi2;
            #pragma unroll
            for (int ni = 0; ni < 4; ++ni) {
                const int col = colbase + ni * 16 + l16;
                if (col < NCOLS) {
                    #pragma unroll
                    for (int r = 0; r < 4; ++r)
                        eps[(mi2 * 16 + quad * 4 + r) * 409 + col] = acc[mi][ni][r] + bias[ni];
                }
            }
        }
        __syncthreads();
        const int row0 = rowbase + h * 32;
        for (int idx = tid; idx < 32 * SCORE_COLS; idx += 512) {
            int r = idx / SCORE_COLS, c = idx - r * SCORE_COLS;
            out[(size_t)(row0 + r) * SCORE_COLS + c] = eps[r * 409 + c];
        }
        for (int idx = tid; idx < 32 * BBOX_COLS; idx += 512) {
            int r = idx / BBOX_COLS, c = idx - r * BBOX_COLS;
            outb[(size_t)(row0 + r) * BBOX_COLS + c] = eps[r * 409 + SCORE_COLS + c];
        }
    }
}

extern "C" void kernel_launch(void* const* d_in, const int* in_sizes, int n_in,
                              void* d_out, int out_size, void* d_ws, size_t ws_size,
                              hipStream_t stream) {
    const float* x     = (const float*)d_in[0];
    const float* Wcls  = (const float*)d_in[1];
    const float* bcls  = (const float*)d_in[2];
    const float* Wsem  = (const float*)d_in[3];
    const float* bsem  = (const float*)d_in[4];
    const float* Wbbox = (const float*)d_in[5];
    const float* bbbox = (const float*)d_in[6];
    const float* semm  = (const float*)d_in[7];
    float* out = (float*)d_out;

    uint16_t* Wt = (uint16_t*)d_ws;                                  // 512*1024*2 = 1 MB (blocked)
    float*    bt = (float*)((char*)d_ws + (size_t)NPAD * KDIM * 2);  // 2 KB

    fill_w<<<dim3(2048), dim3(256), 0, stream>>>(Wcls, bcls, Wbbox, bbbox, Wt, bt);
    fill_w_sem<<<dim3(80, 4), dim3(256), 0, stream>>>(Wsem, bsem, semm, Wt, bt);
    gemm_fused<<<dim3(1024), dim3(512), 0, stream>>>(x, Wt, bt, out);
}